// Round 20
// baseline (62.641 us; speedup 1.0000x reference)
//
#include <hip/hip_runtime.h>
#include <hip/hip_bf16.h>

// ROUND 20: evacuate Wd work from the 4-block k6 via Yd = HW2row @ Wd
// precomputed per-slot in k5b (140 blocks). k6 becomes ~35 L2 row-reads.
// kz computes the constant b2@Wd halves in 2 extra blocks.

#define NN 20000
#define EE 320000
#define E4 (EE/4)
#define KK 4
#define FIN 512
#define FHID 256
#define FOUT 128
#define FHD 256
#define NH (2*FOUT+3)   // 259
#define CAP1 1024
#define MS2 128
#define BCAP 256
#define BMW 640

__device__ __forceinline__ float dinvf(int indeg) {
  // reference deg includes the self-loop -> always >= 1
  return rsqrtf((float)(indeg + 1));
}

// KZ: blocks [0,nzb) zero the counter region; blocks nzb,nzb+1 compute b2@Wd halves.
__global__ __launch_bounds__(256) void kz_zero(int4* __restrict__ p, int n4,
                                               const float* __restrict__ b2,
                                               const float* __restrict__ Wd,
                                               float* __restrict__ b2Wd) {
  int nzb = (n4 + 255) >> 8;
  int b = blockIdx.x;
  if (b < nzb) {
    int i = b * 256 + threadIdx.x;
    if (i < n4) p[i] = make_int4(0, 0, 0, 0);
    return;
  }
  int half = b - nzb;   // 0 or 1
  int jj = threadIdx.x;
  float acc = 0.f;
  const float* wd = Wd + (size_t)(half * 128) * FHD + jj;
  #pragma unroll 8
  for (int kk = 0; kk < 128; kk++) acc += b2[kk] * wd[(size_t)kk * FHD];
  b2Wd[half * FHD + jj] = acc;
}

// K12: scan dst planes; collect L1 edges, CAS-claim slot nodes, set slot bitmap.
__global__ __launch_bounds__(256) void k12_scan_claim(const int* __restrict__ ei,
                                                      const int* __restrict__ idx,
                                                      int* __restrict__ cnt1,
                                                      int* __restrict__ L1src,
                                                      int* __restrict__ L1sel,
                                                      int* __restrict__ reg,
                                                      int* __restrict__ slotNode,
                                                      int* __restrict__ mslots,
                                                      unsigned* __restrict__ bA) {
  int k = blockIdx.y;
  int* rk = reg + (size_t)k * NN;
  unsigned* bAk = bA + k * BMW;
  int t0 = idx[2 * k], t1 = idx[2 * k + 1];
  if (blockIdx.x == 0 && threadIdx.x < 2) {
    int node = (threadIdx.x == 0) ? t0 : t1;
    if (atomicCAS(&rk[node], 0, -2) == 0) {
      int s = atomicAdd(&mslots[k], 1);
      if (s < MS2) {
        slotNode[k * MS2 + s] = node; rk[node] = s + 1;
        atomicOr(&bAk[node >> 5], 1u << (node & 31));
      }
    }
  }
  int e4 = blockIdx.x * blockDim.x + threadIdx.x;
  if (e4 >= E4) return;
  const int* srcp = ei + (size_t)k * 2 * EE;
  int4 d4 = ((const int4*)(srcp + EE))[e4];
  int ds[4] = {d4.x, d4.y, d4.z, d4.w};
  #pragma unroll
  for (int c = 0; c < 4; c++) {
    bool h0 = (ds[c] == t0), h1 = (ds[c] == t1);
    if (h0 || h1) {
      int u = srcp[e4 * 4 + c];
      if (h0) {
        int p = atomicAdd(&cnt1[k], 1);
        if (p < CAP1) { L1src[k * CAP1 + p] = u; L1sel[k * CAP1 + p] = 0; }
      }
      if (h1) {
        int p = atomicAdd(&cnt1[k], 1);
        if (p < CAP1) { L1src[k * CAP1 + p] = u; L1sel[k * CAP1 + p] = 1; }
      }
      if (atomicCAS(&rk[u], 0, -2) == 0) {
        int s = atomicAdd(&mslots[k], 1);
        if (s < MS2) {
          slotNode[k * MS2 + s] = u; rk[u] = s + 1;
          atomicOr(&bAk[u >> 5], 1u << (u & 31));
        }
      }
    }
  }
}

// K3: scan with LDS slot-bitmap membership test; bucket append + bB mark.
__global__ __launch_bounds__(256) void k3_scanL2(const int* __restrict__ ei,
                                                 const int* __restrict__ reg,
                                                 const unsigned* __restrict__ bA,
                                                 unsigned* __restrict__ bB,
                                                 int* __restrict__ bcnt,
                                                 int* __restrict__ bucket) {
  __shared__ unsigned lbA[BMW];   // 2.5 KB
  int k = blockIdx.y;
  const unsigned* bAk = bA + k * BMW;
  for (int i = threadIdx.x; i < BMW; i += 256) lbA[i] = bAk[i];
  __syncthreads();
  int e4 = blockIdx.x * blockDim.x + threadIdx.x;
  if (e4 >= E4) return;
  const int* srcp = ei + (size_t)k * 2 * EE;
  int4 d4 = ((const int4*)(srcp + EE))[e4];
  const int* rk = reg + (size_t)k * NN;
  unsigned* bBk = bB + k * BMW;
  int ds[4] = {d4.x, d4.y, d4.z, d4.w};
  #pragma unroll
  for (int c = 0; c < 4; c++) {
    int d = ds[c];
    if ((lbA[d >> 5] >> (d & 31)) & 1u) {
      int s = rk[d] - 1;
      int u = srcp[e4 * 4 + c];
      int p = atomicAdd(&bcnt[k * MS2 + s], 1);
      if (p < BCAP) bucket[((size_t)k * MS2 + s) * BCAP + p] = u;
      atomicOr(&bBk[u >> 5], 1u << (u & 31));
    }
  }
}

// K4: scan with LDS deg-needed-bitmap test; sparse atomicAdd for hits only.
__global__ __launch_bounds__(256) void k4_deg(const int* __restrict__ ei,
                                              const unsigned* __restrict__ bB,
                                              int* __restrict__ deg) {
  __shared__ unsigned lbB[BMW];
  int k = blockIdx.y;
  const unsigned* bBk = bB + k * BMW;
  for (int i = threadIdx.x; i < BMW; i += 256) lbB[i] = bBk[i];
  __syncthreads();
  int e4 = blockIdx.x * blockDim.x + threadIdx.x;
  if (e4 >= E4) return;
  const int4* dst4 = (const int4*)(ei + (size_t)k * 2 * EE + EE);
  int4 d4 = dst4[e4];
  int ds[4] = {d4.x, d4.y, d4.z, d4.w};
  #pragma unroll
  for (int c = 0; c < 4; c++) {
    int d = ds[c];
    if ((lbB[d >> 5] >> (d & 31)) & 1u) atomicAdd(&deg[k * NN + d], 1);
  }
}

// K5A: one block per (slot, quarter): gather 128-float agg slice + GEMV1 partial.
__global__ __launch_bounds__(256) void k5a_gemv1(const int* __restrict__ slotNode,
                                                 const int* __restrict__ mslots,
                                                 const int* __restrict__ bcnt,
                                                 const int* __restrict__ bucket,
                                                 const int* __restrict__ deg,
                                                 const float* __restrict__ x,
                                                 const float* __restrict__ W1,
                                                 float* __restrict__ partQ) {
  __shared__ int   uS[BCAP];
  __shared__ float duS[BCAP];
  __shared__ float aggq[128];
  __shared__ float gtmp[128];
  int k = blockIdx.y;
  int s = blockIdx.x >> 2, q = blockIdx.x & 3;
  if (s >= mslots[k]) return;
  int tid = threadIdx.x;
  int node = slotNode[k * MS2 + s];
  int rawbc = bcnt[k * MS2 + s];
  int nb = min(rawbc, BCAP);
  const int* bk = bucket + ((size_t)k * MS2 + s) * BCAP;
  if (tid < nb) {
    int u = bk[tid];
    uS[tid] = u;
    duS[tid] = dinvf(deg[k * NN + u]);
  }
  __syncthreads();
  float dn = dinvf(rawbc);   // slot in-degree == bucket count (validated r13+)
  int f = tid & 127, g = tid >> 7;
  const float* xq = x + q * 128 + f;
  float a = (g == 0) ? dn * xq[(size_t)node * FIN] : 0.f;
  for (int e = g; e < nb; e += 2) a += duS[e] * xq[(size_t)uS[e] * FIN];
  if (g == 1) gtmp[f] = a;
  __syncthreads();
  if (g == 0) aggq[f] = dn * (a + gtmp[f]);
  __syncthreads();
  float acc = 0.f;
  const float* w1p = W1 + (size_t)(q * 128) * FHID + tid;
  #pragma unroll 8
  for (int kk = 0; kk < 128; kk++) acc += aggq[kk] * w1p[(size_t)kk * FHID];
  partQ[(((size_t)k * MS2 + s) * 4 + q) * FHID + tid] = acc;
}

// K5B: per slot: hrow = relu(sum partQ + b1); HW2row = hrow@W2 (in LDS);
// then Yd0/Yd1 = HW2row @ Wd_top/bottom -> global (k6's heavy work, moved here).
__global__ __launch_bounds__(256) void k5b_gemv2(const int* __restrict__ mslots,
                                                 const float* __restrict__ partQ,
                                                 const float* __restrict__ b1,
                                                 const float* __restrict__ W2,
                                                 const float* __restrict__ Wd,
                                                 float* __restrict__ Yd) {
  __shared__ float hrow[FHID];
  __shared__ float pr[FHID];
  __shared__ float hw2S[FOUT];
  int k = blockIdx.y, s = blockIdx.x;
  if (s >= mslots[k]) return;
  int tid = threadIdx.x;
  const float* pq = partQ + (((size_t)k * MS2 + s) * 4) * FHID;
  {
    float v = pq[tid] + pq[FHID + tid] + pq[2 * FHID + tid] + pq[3 * FHID + tid] + b1[tid];
    hrow[tid] = v > 0.f ? v : 0.f;
  }
  __syncthreads();
  int half = tid >> 7, j = tid & 127;
  float a = 0.f;
  const float* w2p = W2 + (size_t)(half * 128) * FOUT + j;
  #pragma unroll 8
  for (int kk = 0; kk < 128; kk++) a += hrow[half * 128 + kk] * w2p[(size_t)kk * FOUT];
  pr[tid] = a;
  __syncthreads();
  if (half == 0) hw2S[j] = pr[j] + pr[128 + j];
  __syncthreads();
  // Yd: per-slot decoder-layer-1 contributions
  float y0 = 0.f, y1 = 0.f;
  const float* wd0 = Wd + tid;
  const float* wd1 = Wd + (size_t)128 * FHD + tid;
  #pragma unroll 4
  for (int kk = 0; kk < FOUT; kk++) {
    float hv = hw2S[kk];
    y0 += hv * wd0[(size_t)kk * FHD];
    y1 += hv * wd1[(size_t)kk * FHD];
  }
  float* ydp = Yd + ((size_t)(k * MS2 + s) * 2) * FHD;
  ydp[tid] = y0;
  ydp[FHD + tid] = y1;
}

// K6: tiny decode — sum Yd rows with coefficients + constants, relu, dot(Wp), sigmoid.
__global__ __launch_bounds__(256) void k6_decode(const float* __restrict__ Yd,
                                                 const float* __restrict__ b2Wd,
                                                 const int* __restrict__ cnt1,
                                                 const int* __restrict__ L1src,
                                                 const int* __restrict__ L1sel,
                                                 const int* __restrict__ idx,
                                                 const int* __restrict__ reg,
                                                 const int* __restrict__ bcnt,
                                                 const float* __restrict__ value,
                                                 const float* __restrict__ Wd,
                                                 const float* __restrict__ bd,
                                                 const float* __restrict__ Wp,
                                                 const float* __restrict__ bp,
                                                 float* __restrict__ out) {
  __shared__ float red[4];
  int k = blockIdx.x;
  int tid = threadIdx.x;
  const int* rk = reg + (size_t)k * NN;
  int n1 = min(cnt1[k], CAP1);
  int t0 = idx[2 * k], t1 = idx[2 * k + 1];
  int ts0 = rk[t0] - 1, ts1 = rk[t1] - 1;
  float dit0 = dinvf(bcnt[k * MS2 + ts0]);
  float dit1 = dinvf(bcnt[k * MS2 + ts1]);
  float acc = bd[tid] + b2Wd[tid] + b2Wd[FHD + tid];
  acc += value[3 * k + 0] * Wd[(size_t)256 * FHD + tid]
       + value[3 * k + 1] * Wd[(size_t)257 * FHD + tid]
       + value[3 * k + 2] * Wd[(size_t)258 * FHD + tid];
  const float* ydb = Yd + (size_t)k * MS2 * 2 * FHD;
  acc += dit0 * dit0 * ydb[(size_t)ts0 * 2 * FHD + tid];
  acc += dit1 * dit1 * ydb[(size_t)ts1 * 2 * FHD + FHD + tid];
  for (int i = 0; i < n1; i++) {
    int sn = L1src[k * CAP1 + i];
    int ts = L1sel[k * CAP1 + i];
    int ss = rk[sn] - 1;
    float dis = dinvf(bcnt[k * MS2 + ss]);
    float dit = ts ? dit1 : dit0;
    acc += dis * dit * ydb[((size_t)ss * 2 + ts) * FHD + tid];
  }
  float o = acc > 0.f ? acc : 0.f;
  float r = o * Wp[tid];
  for (int o2 = 32; o2 > 0; o2 >>= 1) r += __shfl_down(r, o2);
  if ((tid & 63) == 0) red[tid >> 6] = r;
  __syncthreads();
  if (tid == 0) {
    float ssum = red[0] + red[1] + red[2] + red[3] + bp[0];
    out[k] = 1.f / (1.f + expf(-ssum));
  }
}

extern "C" void kernel_launch(void* const* d_in, const int* in_sizes, int n_in,
                              void* d_out, int out_size, void* d_ws, size_t ws_size,
                              hipStream_t stream) {
  const float* x     = (const float*)d_in[0];
  const int*   ei    = (const int*)d_in[1];
  const float* value = (const float*)d_in[2];
  const int*   idx   = (const int*)d_in[3];
  const float* W1    = (const float*)d_in[4];
  const float* b1    = (const float*)d_in[5];
  const float* W2    = (const float*)d_in[6];
  const float* b2    = (const float*)d_in[7];
  const float* Wd    = (const float*)d_in[8];
  const float* bd    = (const float*)d_in[9];
  const float* Wp    = (const float*)d_in[10];
  const float* bp    = (const float*)d_in[11];
  float* out = (float*)d_out;

  char* ws = (char*)d_ws;
  size_t off = 0;
  auto alloc = [&](size_t bytes) -> void* {
    void* p = ws + off;
    off = (off + bytes + 255) & ~(size_t)255;
    return p;
  };
  // --- zeroed region (kz): reg, deg, bA, bB, bcnt, cnt1, mslots ---
  size_t zints = (size_t)(2 * KK * NN + 2 * KK * BMW + KK * MS2 + 2 * KK);
  int* reg   = (int*)alloc(zints * sizeof(int));
  int* deg   = reg + KK * NN;
  unsigned* bA = (unsigned*)(deg + KK * NN);
  unsigned* bB = bA + KK * BMW;
  int* bcnt  = (int*)(bB + KK * BMW);
  int* cnt1  = bcnt + KK * MS2;
  int* mslots = cnt1 + KK;
  size_t zbytes = zints * sizeof(int);
  // --- non-zeroed scratch ---
  int* L1src = (int*)alloc((size_t)KK * CAP1 * sizeof(int));
  int* L1sel = (int*)alloc((size_t)KK * CAP1 * sizeof(int));
  int* slotNode = (int*)alloc((size_t)KK * MS2 * sizeof(int));
  int* bucket = (int*)alloc((size_t)KK * MS2 * BCAP * sizeof(int));
  float* partQ = (float*)alloc((size_t)KK * MS2 * 4 * FHID * sizeof(float));  // 2 MB
  float* Yd = (float*)alloc((size_t)KK * MS2 * 2 * FHD * sizeof(float));      // 1 MB
  float* b2Wd = (float*)alloc((size_t)2 * FHD * sizeof(float));
  (void)ws_size; (void)in_sizes; (void)n_in; (void)out_size;

  int n4 = (int)((zbytes + 15) / 16);
  int nzb = (n4 + 255) / 256;
  dim3 escan((E4 + 255) / 256, KK);

  kz_zero<<<nzb + 2, 256, 0, stream>>>((int4*)reg, n4, b2, Wd, b2Wd);
  k12_scan_claim<<<escan, 256, 0, stream>>>(ei, idx, cnt1, L1src, L1sel,
                                            reg, slotNode, mslots, bA);
  k3_scanL2<<<escan, 256, 0, stream>>>(ei, reg, bA, bB, bcnt, bucket);
  k4_deg<<<escan, 256, 0, stream>>>(ei, bB, deg);
  k5a_gemv1<<<dim3(MS2 * 4, KK), 256, 0, stream>>>(slotNode, mslots, bcnt, bucket,
                                                   deg, x, W1, partQ);
  k5b_gemv2<<<dim3(MS2, KK), 256, 0, stream>>>(mslots, partQ, b1, W2, Wd, Yd);
  k6_decode<<<dim3(KK), 256, 0, stream>>>(Yd, b2Wd, cnt1, L1src, L1sel, idx, reg,
                                          bcnt, value, Wd, bd, Wp, bp, out);
}

// Round 21
// 57.300 us; speedup vs baseline: 1.0932x; 1.0932x over previous
//
#include <hip/hip_runtime.h>
#include <hip/hip_bf16.h>

// ROUND 21: r15 base; k6 rewritten — PARALLEL resolve of L1 entries (was a
// ~32-iteration serial dependent-scatter loop, est. ~25µs on a 4-block grid).

#define NN 20000
#define EE 320000
#define E4 (EE/4)
#define KK 4
#define FIN 512
#define FHID 256
#define FOUT 128
#define FHD 256
#define NH (2*FOUT+3)   // 259
#define CAP1 1024
#define MS2 128
#define BCAP 256
#define BMW 640

__device__ __forceinline__ float dinvf(int indeg) {
  // reference deg includes the self-loop -> always >= 1
  return rsqrtf((float)(indeg + 1));
}

__global__ __launch_bounds__(256) void kz_zero(int4* __restrict__ p, int n4) {
  int i = blockIdx.x * 256 + threadIdx.x;
  if (i < n4) p[i] = make_int4(0, 0, 0, 0);
}

// K12: scan dst planes; collect L1 edges, CAS-claim slot nodes, set slot bitmap.
__global__ __launch_bounds__(256) void k12_scan_claim(const int* __restrict__ ei,
                                                      const int* __restrict__ idx,
                                                      int* __restrict__ cnt1,
                                                      int* __restrict__ L1src,
                                                      int* __restrict__ L1sel,
                                                      int* __restrict__ reg,
                                                      int* __restrict__ slotNode,
                                                      int* __restrict__ mslots,
                                                      unsigned* __restrict__ bA) {
  int k = blockIdx.y;
  int* rk = reg + (size_t)k * NN;
  unsigned* bAk = bA + k * BMW;
  int t0 = idx[2 * k], t1 = idx[2 * k + 1];
  if (blockIdx.x == 0 && threadIdx.x < 2) {
    int node = (threadIdx.x == 0) ? t0 : t1;
    if (atomicCAS(&rk[node], 0, -2) == 0) {
      int s = atomicAdd(&mslots[k], 1);
      if (s < MS2) {
        slotNode[k * MS2 + s] = node; rk[node] = s + 1;
        atomicOr(&bAk[node >> 5], 1u << (node & 31));
      }
    }
  }
  int e4 = blockIdx.x * blockDim.x + threadIdx.x;
  if (e4 >= E4) return;
  const int* srcp = ei + (size_t)k * 2 * EE;
  int4 d4 = ((const int4*)(srcp + EE))[e4];
  int ds[4] = {d4.x, d4.y, d4.z, d4.w};
  #pragma unroll
  for (int c = 0; c < 4; c++) {
    bool h0 = (ds[c] == t0), h1 = (ds[c] == t1);
    if (h0 || h1) {
      int u = srcp[e4 * 4 + c];
      if (h0) {
        int p = atomicAdd(&cnt1[k], 1);
        if (p < CAP1) { L1src[k * CAP1 + p] = u; L1sel[k * CAP1 + p] = 0; }
      }
      if (h1) {
        int p = atomicAdd(&cnt1[k], 1);
        if (p < CAP1) { L1src[k * CAP1 + p] = u; L1sel[k * CAP1 + p] = 1; }
      }
      if (atomicCAS(&rk[u], 0, -2) == 0) {
        int s = atomicAdd(&mslots[k], 1);
        if (s < MS2) {
          slotNode[k * MS2 + s] = u; rk[u] = s + 1;
          atomicOr(&bAk[u >> 5], 1u << (u & 31));
        }
      }
    }
  }
}

// K3: scan with LDS slot-bitmap membership test; bucket append + bB mark.
__global__ __launch_bounds__(256) void k3_scanL2(const int* __restrict__ ei,
                                                 const int* __restrict__ reg,
                                                 const unsigned* __restrict__ bA,
                                                 unsigned* __restrict__ bB,
                                                 int* __restrict__ bcnt,
                                                 int* __restrict__ bucket) {
  __shared__ unsigned lbA[BMW];   // 2.5 KB
  int k = blockIdx.y;
  const unsigned* bAk = bA + k * BMW;
  for (int i = threadIdx.x; i < BMW; i += 256) lbA[i] = bAk[i];
  __syncthreads();
  int e4 = blockIdx.x * blockDim.x + threadIdx.x;
  if (e4 >= E4) return;
  const int* srcp = ei + (size_t)k * 2 * EE;
  int4 d4 = ((const int4*)(srcp + EE))[e4];
  const int* rk = reg + (size_t)k * NN;
  unsigned* bBk = bB + k * BMW;
  int ds[4] = {d4.x, d4.y, d4.z, d4.w};
  #pragma unroll
  for (int c = 0; c < 4; c++) {
    int d = ds[c];
    if ((lbA[d >> 5] >> (d & 31)) & 1u) {
      int s = rk[d] - 1;
      int u = srcp[e4 * 4 + c];
      int p = atomicAdd(&bcnt[k * MS2 + s], 1);
      if (p < BCAP) bucket[((size_t)k * MS2 + s) * BCAP + p] = u;
      atomicOr(&bBk[u >> 5], 1u << (u & 31));
    }
  }
}

// K4: scan with LDS deg-needed-bitmap test; sparse atomicAdd for hits only.
__global__ __launch_bounds__(256) void k4_deg(const int* __restrict__ ei,
                                              const unsigned* __restrict__ bB,
                                              int* __restrict__ deg) {
  __shared__ unsigned lbB[BMW];
  int k = blockIdx.y;
  const unsigned* bBk = bB + k * BMW;
  for (int i = threadIdx.x; i < BMW; i += 256) lbB[i] = bBk[i];
  __syncthreads();
  int e4 = blockIdx.x * blockDim.x + threadIdx.x;
  if (e4 >= E4) return;
  const int4* dst4 = (const int4*)(ei + (size_t)k * 2 * EE + EE);
  int4 d4 = dst4[e4];
  int ds[4] = {d4.x, d4.y, d4.z, d4.w};
  #pragma unroll
  for (int c = 0; c < 4; c++) {
    int d = ds[c];
    if ((lbB[d >> 5] >> (d & 31)) & 1u) atomicAdd(&deg[k * NN + d], 1);
  }
}

// K5: r15 body (8-way float4 gather + LDS reduce + GEMV1 + relu + GEMV2).
__global__ __launch_bounds__(1024) void k5_slotmlp(const int* __restrict__ slotNode,
                                                   const int* __restrict__ mslots,
                                                   const int* __restrict__ bcnt,
                                                   const int* __restrict__ bucket,
                                                   const int* __restrict__ deg,
                                                   const float* __restrict__ x,
                                                   const float* __restrict__ W1,
                                                   const float* __restrict__ b1,
                                                   const float* __restrict__ W2,
                                                   float* __restrict__ HW2) {
  __shared__ float partg[8][FIN];
  __shared__ float aggS[FIN];
  __shared__ float part[4][FHID];
  __shared__ float hrow[FHID];
  __shared__ float part2[8][FOUT];
  __shared__ int   uS[BCAP];
  __shared__ float duS[BCAP];
  int k = blockIdx.y, s = blockIdx.x;
  if (s >= mslots[k]) return;
  int tid = threadIdx.x;
  int node = slotNode[k * MS2 + s];
  int rawbc = bcnt[k * MS2 + s];
  int nb = min(rawbc, BCAP);
  const int* bk = bucket + ((size_t)k * MS2 + s) * BCAP;
  if (tid < nb) {
    int u = bk[tid];
    uS[tid] = u;
    duS[tid] = dinvf(deg[k * NN + u]);
  }
  __syncthreads();
  float dn = dinvf(rawbc);   // slot in-degree == bucket count (validated r13+)
  int g = tid >> 7, f4 = tid & 127;
  float ax = 0.f, ay = 0.f, az = 0.f, aw = 0.f;
  if (g == 0) {
    float4 v = ((const float4*)(x + (size_t)node * FIN))[f4];
    ax = dn * v.x; ay = dn * v.y; az = dn * v.z; aw = dn * v.w;
  }
  for (int e = g; e < nb; e += 8) {
    float du = duS[e];
    float4 v = ((const float4*)(x + (size_t)uS[e] * FIN))[f4];
    ax += du * v.x; ay += du * v.y; az += du * v.z; aw += du * v.w;
  }
  { float* pw = &partg[g][f4 * 4]; pw[0] = ax; pw[1] = ay; pw[2] = az; pw[3] = aw; }
  __syncthreads();
  if (tid < FIN) {
    float ssum = 0.f;
    #pragma unroll
    for (int g2 = 0; g2 < 8; g2++) ssum += partg[g2][tid];
    aggS[tid] = dn * ssum;
  }
  __syncthreads();
  {
    int q = tid >> 8, j = tid & (FHID - 1);
    float acc = 0.f;
    const float* w1p = W1 + (size_t)(q * 128) * FHID + j;
    const float* ap = aggS + q * 128;
    #pragma unroll 8
    for (int kk = 0; kk < 128; kk++) acc += ap[kk] * w1p[(size_t)kk * FHID];
    part[q][j] = acc;
  }
  __syncthreads();
  if (tid < FHID) {
    float v = part[0][tid] + part[1][tid] + part[2][tid] + part[3][tid] + b1[tid];
    hrow[tid] = v > 0.f ? v : 0.f;
  }
  __syncthreads();
  {
    int p = tid >> 7, j = tid & (FOUT - 1);
    float a2 = 0.f;
    const float* w2p = W2 + (size_t)(p * 32) * FOUT + j;
    const float* hp = hrow + p * 32;
    #pragma unroll 8
    for (int kk = 0; kk < 32; kk++) a2 += hp[kk] * w2p[(size_t)kk * FOUT];
    part2[p][j] = a2;
  }
  __syncthreads();
  if (tid < FOUT) {
    float sv = part2[0][tid] + part2[1][tid] + part2[2][tid] + part2[3][tid] +
               part2[4][tid] + part2[5][tid] + part2[6][tid] + part2[7][tid];
    HW2[((size_t)k * MS2 + s) * FOUT + tid] = sv;
  }
}

// K6 (REWRITTEN): phase 1 = parallel resolve of L1 entries (one thread per
// entry, concurrent scattered loads -> LDS). Phase 2 = per-column accumulate
// with independent coalesced HW2 row loads. Then decoder as before.
__global__ __launch_bounds__(256) void k6_decode(const float* __restrict__ HW2,
                                                 const float* __restrict__ b2,
                                                 const int* __restrict__ cnt1,
                                                 const int* __restrict__ L1src,
                                                 const int* __restrict__ L1sel,
                                                 const int* __restrict__ idx,
                                                 const int* __restrict__ reg,
                                                 const int* __restrict__ bcnt,
                                                 const float* __restrict__ value,
                                                 const float* __restrict__ Wd,
                                                 const float* __restrict__ bd,
                                                 const float* __restrict__ Wp,
                                                 const float* __restrict__ bp,
                                                 float* __restrict__ out) {
  __shared__ float coefS[CAP1 + 2];   // 4.1 KB
  __shared__ short slotS[CAP1 + 2];   // 2.05 KB
  __shared__ short tselS[CAP1 + 2];   // 2.05 KB
  __shared__ float hD[NH + 1];
  __shared__ float red[4];
  int k = blockIdx.x;
  int tid = threadIdx.x;
  const int* rk = reg + (size_t)k * NN;
  int n1 = min(cnt1[k], CAP1);
  int t0 = idx[2 * k], t1 = idx[2 * k + 1];
  int ts0 = rk[t0] - 1, ts1 = rk[t1] - 1;
  float dit0 = dinvf(bcnt[k * MS2 + ts0]);
  float dit1 = dinvf(bcnt[k * MS2 + ts1]);
  // phase 1: parallel resolve (independent scattered loads across threads)
  for (int i = tid; i < n1; i += 256) {
    int sn = L1src[k * CAP1 + i];
    int ts = L1sel[k * CAP1 + i];
    int ss = rk[sn] - 1;
    float dis = dinvf(bcnt[k * MS2 + ss]);
    coefS[i] = dis * (ts ? dit1 : dit0);
    slotS[i] = (short)ss;
    tselS[i] = (short)ts;
  }
  if (tid == 0) {
    coefS[n1] = dit0 * dit0; slotS[n1] = (short)ts0; tselS[n1] = 0;
    coefS[n1 + 1] = dit1 * dit1; slotS[n1 + 1] = (short)ts1; tselS[n1 + 1] = 1;
  }
  __syncthreads();
  // phase 2: accumulate mu halves; loads independent across i, coalesced in j
  {
    int tsel = tid >> 7, j = tid & 127;
    float acc = b2[j];
    int m = n1 + 2;
    for (int i = 0; i < m; i++) {
      if ((int)tselS[i] == tsel)
        acc += coefS[i] * HW2[((size_t)k * MS2 + (int)slotS[i]) * FOUT + j];
    }
    hD[tid] = acc;
    if (tid < 3) hD[2 * FOUT + tid] = value[k * 3 + tid];
  }
  __syncthreads();
  // decoder layer 1 (259 -> 256), independent coalesced Wd row loads
  float a2 = bd[tid];
  for (int i = 0; i < NH; i++) a2 += hD[i] * Wd[(size_t)i * FHD + tid];
  float o = a2 > 0.f ? a2 : 0.f;
  float r = o * Wp[tid];
  for (int o2 = 32; o2 > 0; o2 >>= 1) r += __shfl_down(r, o2);
  if ((tid & 63) == 0) red[tid >> 6] = r;
  __syncthreads();
  if (tid == 0) {
    float ssum = red[0] + red[1] + red[2] + red[3] + bp[0];
    out[k] = 1.f / (1.f + expf(-ssum));
  }
}

extern "C" void kernel_launch(void* const* d_in, const int* in_sizes, int n_in,
                              void* d_out, int out_size, void* d_ws, size_t ws_size,
                              hipStream_t stream) {
  const float* x     = (const float*)d_in[0];
  const int*   ei    = (const int*)d_in[1];
  const float* value = (const float*)d_in[2];
  const int*   idx   = (const int*)d_in[3];
  const float* W1    = (const float*)d_in[4];
  const float* b1    = (const float*)d_in[5];
  const float* W2    = (const float*)d_in[6];
  const float* b2    = (const float*)d_in[7];
  const float* Wd    = (const float*)d_in[8];
  const float* bd    = (const float*)d_in[9];
  const float* Wp    = (const float*)d_in[10];
  const float* bp    = (const float*)d_in[11];
  float* out = (float*)d_out;

  char* ws = (char*)d_ws;
  size_t off = 0;
  auto alloc = [&](size_t bytes) -> void* {
    void* p = ws + off;
    off = (off + bytes + 255) & ~(size_t)255;
    return p;
  };
  // --- zeroed region (one kz_zero): reg, deg, bA, bB, bcnt, cnt1, mslots ---
  size_t zints = (size_t)(2 * KK * NN + 2 * KK * BMW + KK * MS2 + 2 * KK);
  int* reg   = (int*)alloc(zints * sizeof(int));
  int* deg   = reg + KK * NN;
  unsigned* bA = (unsigned*)(deg + KK * NN);
  unsigned* bB = bA + KK * BMW;
  int* bcnt  = (int*)(bB + KK * BMW);
  int* cnt1  = bcnt + KK * MS2;
  int* mslots = cnt1 + KK;
  size_t zbytes = zints * sizeof(int);
  // --- non-zeroed scratch ---
  int* L1src = (int*)alloc((size_t)KK * CAP1 * sizeof(int));
  int* L1sel = (int*)alloc((size_t)KK * CAP1 * sizeof(int));
  int* slotNode = (int*)alloc((size_t)KK * MS2 * sizeof(int));
  int* bucket = (int*)alloc((size_t)KK * MS2 * BCAP * sizeof(int));
  float* HW2 = (float*)alloc((size_t)KK * MS2 * FOUT * sizeof(float));
  (void)ws_size; (void)in_sizes; (void)n_in; (void)out_size;

  int n4 = (int)((zbytes + 15) / 16);
  dim3 escan((E4 + 255) / 256, KK);

  kz_zero<<<(n4 + 255) / 256, 256, 0, stream>>>((int4*)reg, n4);
  k12_scan_claim<<<escan, 256, 0, stream>>>(ei, idx, cnt1, L1src, L1sel,
                                            reg, slotNode, mslots, bA);
  k3_scanL2<<<escan, 256, 0, stream>>>(ei, reg, bA, bB, bcnt, bucket);
  k4_deg<<<escan, 256, 0, stream>>>(ei, bB, deg);
  k5_slotmlp<<<dim3(MS2, KK), 1024, 0, stream>>>(slotNode, mslots, bcnt, bucket, deg,
                                                 x, W1, b1, W2, HW2);
  k6_decode<<<dim3(KK), 256, 0, stream>>>(HW2, b2, cnt1, L1src, L1sel, idx, reg, bcnt,
                                          value, Wd, bd, Wp, bp, out);
}